// Round 4
// baseline (473.793 us; speedup 1.0000x reference)
//
#include <hip/hip_runtime.h>

// GraphEncoder: 3x (GCNConv -> [ReLU -> LayerNorm]) on N=100000 nodes, E=1.6M edges.
// Round 4: (a) fold deg-norm into GEMM epilogue -> eidx is bare 4B src index
//          (b) T stored as bf16 (pre-scaled by dinv) -> halves gather traffic.

constexpr float LN_EPS = 1e-5f;

// ---- bf16 helpers (RNE) ----
__device__ inline unsigned bf1(float x) {
    unsigned u = __float_as_uint(x);
    return (u + 0x7FFFu + ((u >> 16) & 1u)) >> 16;
}
__device__ inline unsigned bfpack(float lo, float hi) { return bf1(lo) | (bf1(hi) << 16); }
__device__ inline float bflo(unsigned r) { return __uint_as_float(r << 16); }
__device__ inline float bfhi(unsigned r) { return __uint_as_float(r & 0xFFFF0000u); }

// ---------------- int degree histogram ----------------
__global__ void deg_kernel(const int* __restrict__ dst, int E, int* __restrict__ deg) {
    int i = blockIdx.x * blockDim.x + threadIdx.x;
    int stride = gridDim.x * blockDim.x;
    for (; i < E; i += stride) atomicAdd(&deg[dst[i]], 1);
}

__global__ void dinv_kernel(const int* __restrict__ deg, float* __restrict__ dinv, int n) {
    int i = blockIdx.x * blockDim.x + threadIdx.x;
    if (i < n) dinv[i] = rsqrtf((float)deg[i] + 1.0f);  // +1 = self loop
}

// ---------------- exclusive scan of deg -> starts ----------------
__global__ __launch_bounds__(256) void scan_block_kernel(const int* __restrict__ deg, int n,
                                                         int* __restrict__ starts,
                                                         int* __restrict__ bsum) {
    __shared__ int wsum[4];
    const int b = blockIdx.x, t = threadIdx.x;
    const int lane = t & 63, w = t >> 6;
    const int base = b * 1024 + t * 4;
    int v0 = (base + 0 < n) ? deg[base + 0] : 0;
    int v1 = (base + 1 < n) ? deg[base + 1] : 0;
    int v2 = (base + 2 < n) ? deg[base + 2] : 0;
    int v3 = (base + 3 < n) ? deg[base + 3] : 0;
    int s = v0 + v1 + v2 + v3;
    int inc = s;
#pragma unroll
    for (int off = 1; off < 64; off <<= 1) {
        int u = __shfl_up(inc, off, 64);
        if (lane >= off) inc += u;
    }
    if (lane == 63) wsum[w] = inc;
    __syncthreads();
    int woff = 0;
#pragma unroll
    for (int i = 0; i < 4; ++i)
        if (i < w) woff += wsum[i];
    int ex = woff + inc - s;
    if (base + 0 < n) starts[base + 0] = ex;
    if (base + 1 < n) starts[base + 1] = ex + v0;
    if (base + 2 < n) starts[base + 2] = ex + v0 + v1;
    if (base + 3 < n) starts[base + 3] = ex + v0 + v1 + v2;
    if (t == 255) bsum[b] = woff + inc;
}

__global__ void scan_bsum_kernel(int* __restrict__ bsum, int nb) {
    __shared__ int w0sum;
    const int t = threadIdx.x, lane = t & 63, w = t >> 6;
    int v = (t < nb) ? bsum[t] : 0;
    int inc = v;
#pragma unroll
    for (int off = 1; off < 64; off <<= 1) {
        int u = __shfl_up(inc, off, 64);
        if (lane >= off) inc += u;
    }
    if (w == 0 && lane == 63) w0sum = inc;
    __syncthreads();
    int ex = inc - v + ((w == 1) ? w0sum : 0);
    if (t < nb) bsum[t] = ex;
}

__global__ __launch_bounds__(256) void add_off_kernel(int* __restrict__ starts,
                                                      const int* __restrict__ bsum,
                                                      int* __restrict__ cursor, int n) {
    const int off = bsum[blockIdx.x];
    const int base = blockIdx.x * 1024 + threadIdx.x * 4;
#pragma unroll
    for (int j = 0; j < 4; ++j) {
        int idx = base + j;
        if (idx < n) {
            int val = starts[idx] + off;
            starts[idx] = val;
            cursor[idx] = val;
        }
    }
}

// ---------------- bucket fill: eidx[pos] = src, grouped by dst ----------------
__global__ __launch_bounds__(256) void fill_kernel(const int* __restrict__ src,
                                                   const int* __restrict__ dst,
                                                   int* __restrict__ cursor,
                                                   int* __restrict__ eidx, int E) {
    int i = blockIdx.x * blockDim.x + threadIdx.x;
    int stride = gridDim.x * blockDim.x;
    for (; i < E; i += stride) {
        int s = src[i], d = dst[i];
        int pos = atomicAdd(&cursor[d], 1);
        eidx[pos] = s;
    }
}

// ---------------- dense GEMM: T[n x 64] = bf16( (X[n x DIN] @ W[DIN x 64]) * dinv[row] ) ----------------
template <int DIN>
__global__ __launch_bounds__(256) void gemm_kernel(const float* __restrict__ X,
                                                   const float* __restrict__ W,
                                                   const float* __restrict__ dinv,
                                                   unsigned short* __restrict__ T, int n) {
    __shared__ float xs[64][33];
    __shared__ float ws[32][64];
    const int t  = threadIdx.x;
    const int n0 = blockIdx.x * 64;
    const int tc = t & 15;
    const int tr = t >> 4;

    float acc[4][4] = {};

    for (int k0 = 0; k0 < DIN; k0 += 32) {
        for (int l = t; l < 512; l += 256) {
            int r = l >> 3;
            int q = (l & 7) << 2;
            int row = n0 + r;
            float4 v = make_float4(0.f, 0.f, 0.f, 0.f);
            if (row < n) v = *reinterpret_cast<const float4*>(&X[(long)row * DIN + k0 + q]);
            xs[r][q + 0] = v.x; xs[r][q + 1] = v.y; xs[r][q + 2] = v.z; xs[r][q + 3] = v.w;
        }
        for (int l = t; l < 512; l += 256) {
            int r = l >> 4;
            int q = (l & 15) << 2;
            float4 v = *reinterpret_cast<const float4*>(&W[(long)(k0 + r) * 64 + q]);
            *reinterpret_cast<float4*>(&ws[r][q]) = v;
        }
        __syncthreads();
#pragma unroll
        for (int k = 0; k < 32; ++k) {
            float4 wv = *reinterpret_cast<const float4*>(&ws[k][tc * 4]);
#pragma unroll
            for (int j = 0; j < 4; ++j) {
                float xv = xs[tr * 4 + j][k];
                acc[j][0] += xv * wv.x;
                acc[j][1] += xv * wv.y;
                acc[j][2] += xv * wv.z;
                acc[j][3] += xv * wv.w;
            }
        }
        __syncthreads();
    }

    for (int j = 0; j < 4; ++j) {
        int row = n0 + tr * 4 + j;
        if (row < n) {
            float di = dinv[row];
            uint2 p;
            p.x = bfpack(acc[j][0] * di, acc[j][1] * di);
            p.y = bfpack(acc[j][2] * di, acc[j][3] * di);
            *reinterpret_cast<uint2*>(&T[(long)row * 64 + tc * 4]) = p;
        }
    }
}

// ---------------- fused gather + self-loop + bias (+ ReLU + LayerNorm) ----------------
// One wave per node. Row is 128B bf16: lanes 0..31 hold channels (2sl, 2sl+1);
// wave halves process alternating edges, combined via shfl_xor(32).
// MODE 0: ReLU+LN -> H (fp32). MODE 1: plain -> out (fp32).
template <int MODE>
__global__ __launch_bounds__(256) void gather_kernel(const unsigned short* __restrict__ T,
                                                     const int* __restrict__ starts,
                                                     const int* __restrict__ eidx,
                                                     const float* __restrict__ dinv,
                                                     const float* __restrict__ b,
                                                     const float* __restrict__ g,
                                                     const float* __restrict__ beta,
                                                     float* __restrict__ out, int n, int E) {
    const int t = threadIdx.x;
    const int lane = t & 63;
    const int sl = lane & 31;
    const int half = lane >> 5;
    const int node = blockIdx.x * 4 + (t >> 6);
    if (node >= n) return;
    int beg = starts[node];
    int end = (node == n - 1) ? E : starts[node + 1];
    beg = __builtin_amdgcn_readfirstlane(beg);
    end = __builtin_amdgcn_readfirstlane(end);

    float a0 = 0.0f, a1 = 0.0f;
    int k = beg;
    // 4 edges per iteration: half 0 takes (k,k+1), half 1 takes (k+2,k+3)
    for (; k + 4 <= end; k += 4) {
        int s0 = eidx[k + 2 * half + 0];
        int s1 = eidx[k + 2 * half + 1];
        unsigned r0 = *reinterpret_cast<const unsigned*>(&T[(long)s0 * 64 + 2 * sl]);
        unsigned r1 = *reinterpret_cast<const unsigned*>(&T[(long)s1 * 64 + 2 * sl]);
        a0 += bflo(r0); a1 += bfhi(r0);
        a0 += bflo(r1); a1 += bfhi(r1);
    }
    if (k + 2 <= end) {
        int s = eidx[k + half];
        unsigned r = *reinterpret_cast<const unsigned*>(&T[(long)s * 64 + 2 * sl]);
        a0 += bflo(r); a1 += bfhi(r);
        k += 2;
    }
    if (k < end && half == 0) {
        int s = eidx[k];
        unsigned r = *reinterpret_cast<const unsigned*>(&T[(long)s * 64 + 2 * sl]);
        a0 += bflo(r); a1 += bfhi(r);
    }
    // combine the two halves
    a0 += __shfl_xor(a0, 32, 64);
    a1 += __shfl_xor(a1, 32, 64);

    // self loop + bias: out = dinv[v]*(sum + T'[v]) + b
    const float di = dinv[node];
    unsigned rs = *reinterpret_cast<const unsigned*>(&T[(long)node * 64 + 2 * sl]);
    float2 bb = *reinterpret_cast<const float2*>(&b[2 * sl]);
    float v0 = di * (a0 + bflo(rs)) + bb.x;
    float v1 = di * (a1 + bfhi(rs)) + bb.y;

    if (MODE == 0) {
        v0 = fmaxf(v0, 0.0f);
        v1 = fmaxf(v1, 0.0f);
        float s = v0 + v1;
#pragma unroll
        for (int off = 16; off > 0; off >>= 1) s += __shfl_xor(s, off, 64);
        float mu = s * (1.0f / 64.0f);
        float d0 = v0 - mu, d1 = v1 - mu;
        float q = d0 * d0 + d1 * d1;
#pragma unroll
        for (int off = 16; off > 0; off >>= 1) q += __shfl_xor(q, off, 64);
        float inv = rsqrtf(q * (1.0f / 64.0f) + LN_EPS);
        float2 gg = *reinterpret_cast<const float2*>(&g[2 * sl]);
        float2 be = *reinterpret_cast<const float2*>(&beta[2 * sl]);
        if (half == 0) {
            float2 o = make_float2(d0 * inv * gg.x + be.x, d1 * inv * gg.y + be.y);
            *reinterpret_cast<float2*>(&out[(long)node * 64 + 2 * sl]) = o;
        }
    } else {
        if (half == 0) {
            *reinterpret_cast<float2*>(&out[(long)node * 64 + 2 * sl]) = make_float2(v0, v1);
        }
    }
}

extern "C" void kernel_launch(void* const* d_in, const int* in_sizes, int n_in,
                              void* d_out, int out_size, void* d_ws, size_t ws_size,
                              hipStream_t stream) {
    const float* x    = (const float*)d_in[0];
    const int*   ei   = (const int*)d_in[1];
    const float* W_in = (const float*)d_in[2];
    const float* b_in = (const float*)d_in[3];
    const float* g_in = (const float*)d_in[4];
    const float* be_in= (const float*)d_in[5];
    const float* W_h  = (const float*)d_in[6];
    const float* b_h  = (const float*)d_in[7];
    const float* g_h  = (const float*)d_in[8];
    const float* be_h = (const float*)d_in[9];
    const float* W_out= (const float*)d_in[10];
    const float* b_out= (const float*)d_in[11];
    float* out = (float*)d_out;

    const int n = in_sizes[0] / 128;   // 100000
    const int E = in_sizes[1] / 2;     // 1600000
    const int* src = ei;
    const int* dst = ei + E;

    // workspace: eidx[E i32] | dinv[NP f] | degi[NP] | starts[NP] | cursor[NP] | bsum[1024] | T[NP*64 u16] | H[NP*64 f]
    const long NP = ((long)n + 127) & ~127L;
    int*   eidx   = (int*)d_ws;
    float* dinv   = (float*)(eidx + E);
    int*   degi   = (int*)(dinv + NP);
    int*   starts = degi + NP;
    int*   cursor = starts + NP;
    int*   bsum   = cursor + NP;
    unsigned short* T = (unsigned short*)(bsum + 1024);
    float* H      = (float*)(T + NP * 64);

    const int nb = (n + 1023) / 1024;  // 98 (<=128 required by scan_bsum)

    // ---- CSR-transpose build (shared by all 3 layers) ----
    hipMemsetAsync(degi, 0, (size_t)n * sizeof(int), stream);
    deg_kernel<<<2048, 256, 0, stream>>>(dst, E, degi);
    dinv_kernel<<<(n + 255) / 256, 256, 0, stream>>>(degi, dinv, n);
    scan_block_kernel<<<nb, 256, 0, stream>>>(degi, n, starts, bsum);
    scan_bsum_kernel<<<1, 128, 0, stream>>>(bsum, nb);
    add_off_kernel<<<nb, 256, 0, stream>>>(starts, bsum, cursor, n);
    fill_kernel<<<2048, 256, 0, stream>>>(src, dst, cursor, eidx, E);

    const int ggrid = (n + 3) / 4;

    // ---- layer 1 ----
    gemm_kernel<128><<<(n + 63) / 64, 256, 0, stream>>>(x, W_in, dinv, T, n);
    gather_kernel<0><<<ggrid, 256, 0, stream>>>(T, starts, eidx, dinv, b_in, g_in, be_in, H, n, E);

    // ---- layer 2 ----
    gemm_kernel<64><<<(n + 63) / 64, 256, 0, stream>>>(H, W_h, dinv, T, n);
    gather_kernel<0><<<ggrid, 256, 0, stream>>>(T, starts, eidx, dinv, b_h, g_h, be_h, H, n, E);

    // ---- layer 3 (no ReLU/LN, straight to output) ----
    gemm_kernel<64><<<(n + 63) / 64, 256, 0, stream>>>(H, W_out, dinv, T, n);
    gather_kernel<1><<<ggrid, 256, 0, stream>>>(T, starts, eidx, dinv, b_out, nullptr, nullptr, out, n, E);
}

// Round 5
// 435.223 us; speedup vs baseline: 1.0886x; 1.0886x over previous
//
#include <hip/hip_runtime.h>

// GraphEncoder: 3x (GCNConv -> [ReLU -> LayerNorm]) on N=100000 nodes, E=1.6M edges.
// Round 5: (a) fill reverted to 8B slots (4B slots caused cross-XCD dirty-line sharing: 85->134us)
//          (b) gather: 8 lanes/row x uint4 -> one VMEM instr gathers 8 edges; unroll x2 = 16 in flight.

constexpr float LN_EPS = 1e-5f;

// ---- bf16 helpers (RNE) ----
__device__ inline unsigned bf1(float x) {
    unsigned u = __float_as_uint(x);
    return (u + 0x7FFFu + ((u >> 16) & 1u)) >> 16;
}
__device__ inline unsigned bfpack(float lo, float hi) { return bf1(lo) | (bf1(hi) << 16); }
__device__ inline float bflo(unsigned r) { return __uint_as_float(r << 16); }
__device__ inline float bfhi(unsigned r) { return __uint_as_float(r & 0xFFFF0000u); }

// ---------------- int degree histogram ----------------
__global__ void deg_kernel(const int* __restrict__ dst, int E, int* __restrict__ deg) {
    int i = blockIdx.x * blockDim.x + threadIdx.x;
    int stride = gridDim.x * blockDim.x;
    for (; i < E; i += stride) atomicAdd(&deg[dst[i]], 1);
}

__global__ void dinv_kernel(const int* __restrict__ deg, float* __restrict__ dinv, int n) {
    int i = blockIdx.x * blockDim.x + threadIdx.x;
    if (i < n) dinv[i] = rsqrtf((float)deg[i] + 1.0f);  // +1 = self loop
}

// ---------------- exclusive scan of deg -> starts ----------------
__global__ __launch_bounds__(256) void scan_block_kernel(const int* __restrict__ deg, int n,
                                                         int* __restrict__ starts,
                                                         int* __restrict__ bsum) {
    __shared__ int wsum[4];
    const int b = blockIdx.x, t = threadIdx.x;
    const int lane = t & 63, w = t >> 6;
    const int base = b * 1024 + t * 4;
    int v0 = (base + 0 < n) ? deg[base + 0] : 0;
    int v1 = (base + 1 < n) ? deg[base + 1] : 0;
    int v2 = (base + 2 < n) ? deg[base + 2] : 0;
    int v3 = (base + 3 < n) ? deg[base + 3] : 0;
    int s = v0 + v1 + v2 + v3;
    int inc = s;
#pragma unroll
    for (int off = 1; off < 64; off <<= 1) {
        int u = __shfl_up(inc, off, 64);
        if (lane >= off) inc += u;
    }
    if (lane == 63) wsum[w] = inc;
    __syncthreads();
    int woff = 0;
#pragma unroll
    for (int i = 0; i < 4; ++i)
        if (i < w) woff += wsum[i];
    int ex = woff + inc - s;
    if (base + 0 < n) starts[base + 0] = ex;
    if (base + 1 < n) starts[base + 1] = ex + v0;
    if (base + 2 < n) starts[base + 2] = ex + v0 + v1;
    if (base + 3 < n) starts[base + 3] = ex + v0 + v1 + v2;
    if (t == 255) bsum[b] = woff + inc;
}

__global__ void scan_bsum_kernel(int* __restrict__ bsum, int nb) {
    __shared__ int w0sum;
    const int t = threadIdx.x, lane = t & 63, w = t >> 6;
    int v = (t < nb) ? bsum[t] : 0;
    int inc = v;
#pragma unroll
    for (int off = 1; off < 64; off <<= 1) {
        int u = __shfl_up(inc, off, 64);
        if (lane >= off) inc += u;
    }
    if (w == 0 && lane == 63) w0sum = inc;
    __syncthreads();
    int ex = inc - v + ((w == 1) ? w0sum : 0);
    if (t < nb) bsum[t] = ex;
}

__global__ __launch_bounds__(256) void add_off_kernel(int* __restrict__ starts,
                                                      const int* __restrict__ bsum,
                                                      int* __restrict__ cursor, int n) {
    const int off = bsum[blockIdx.x];
    const int base = blockIdx.x * 1024 + threadIdx.x * 4;
#pragma unroll
    for (int j = 0; j < 4; ++j) {
        int idx = base + j;
        if (idx < n) {
            int val = starts[idx] + off;
            starts[idx] = val;
            cursor[idx] = val;
        }
    }
}

// ---------------- bucket fill: eidx[pos].x = src, grouped by dst ----------------
// 8B slots on purpose: 4B slots double the concurrent writers per 64B line
// (cross-XCD dirty-line sharing) and measured 85us -> 134us. Keep int2.
__global__ __launch_bounds__(256) void fill_kernel(const int* __restrict__ src,
                                                   const int* __restrict__ dst,
                                                   int* __restrict__ cursor,
                                                   int2* __restrict__ eidx, int E) {
    int i = blockIdx.x * blockDim.x + threadIdx.x;
    int stride = gridDim.x * blockDim.x;
    for (; i < E; i += stride) {
        int s = src[i], d = dst[i];
        int pos = atomicAdd(&cursor[d], 1);
        eidx[pos] = make_int2(s, 0);
    }
}

// ---------------- dense GEMM: T[n x 64] = bf16( (X[n x DIN] @ W[DIN x 64]) * dinv[row] ) ----------------
template <int DIN>
__global__ __launch_bounds__(256) void gemm_kernel(const float* __restrict__ X,
                                                   const float* __restrict__ W,
                                                   const float* __restrict__ dinv,
                                                   unsigned short* __restrict__ T, int n) {
    __shared__ float xs[64][33];
    __shared__ float ws[32][64];
    const int t  = threadIdx.x;
    const int n0 = blockIdx.x * 64;
    const int tc = t & 15;
    const int tr = t >> 4;

    float acc[4][4] = {};

    for (int k0 = 0; k0 < DIN; k0 += 32) {
        for (int l = t; l < 512; l += 256) {
            int r = l >> 3;
            int q = (l & 7) << 2;
            int row = n0 + r;
            float4 v = make_float4(0.f, 0.f, 0.f, 0.f);
            if (row < n) v = *reinterpret_cast<const float4*>(&X[(long)row * DIN + k0 + q]);
            xs[r][q + 0] = v.x; xs[r][q + 1] = v.y; xs[r][q + 2] = v.z; xs[r][q + 3] = v.w;
        }
        for (int l = t; l < 512; l += 256) {
            int r = l >> 4;
            int q = (l & 15) << 2;
            float4 v = *reinterpret_cast<const float4*>(&W[(long)(k0 + r) * 64 + q]);
            *reinterpret_cast<float4*>(&ws[r][q]) = v;
        }
        __syncthreads();
#pragma unroll
        for (int k = 0; k < 32; ++k) {
            float4 wv = *reinterpret_cast<const float4*>(&ws[k][tc * 4]);
#pragma unroll
            for (int j = 0; j < 4; ++j) {
                float xv = xs[tr * 4 + j][k];
                acc[j][0] += xv * wv.x;
                acc[j][1] += xv * wv.y;
                acc[j][2] += xv * wv.z;
                acc[j][3] += xv * wv.w;
            }
        }
        __syncthreads();
    }

    for (int j = 0; j < 4; ++j) {
        int row = n0 + tr * 4 + j;
        if (row < n) {
            float di = dinv[row];
            uint2 p;
            p.x = bfpack(acc[j][0] * di, acc[j][1] * di);
            p.y = bfpack(acc[j][2] * di, acc[j][3] * di);
            *reinterpret_cast<uint2*>(&T[(long)row * 64 + tc * 4]) = p;
        }
    }
}

// ---------------- fused gather + self-loop + bias (+ ReLU + LayerNorm) ----------------
// One wave per node. bf16 row = 128B. Lane = grp*8 + c: grp in [0,8) = edge group,
// c in [0,8) = channel chunk (channels 8c..8c+7, one uint4 = 16B).
// One row-load instruction gathers 8 edges; unroll x2 -> 16 edges in flight/wave.
// MODE 0: ReLU+LN -> H (fp32). MODE 1: plain -> out (fp32).
template <int MODE>
__global__ __launch_bounds__(256) void gather_kernel(const unsigned short* __restrict__ T,
                                                     const int* __restrict__ starts,
                                                     const int2* __restrict__ eidx,
                                                     const float* __restrict__ dinv,
                                                     const float* __restrict__ b,
                                                     const float* __restrict__ g,
                                                     const float* __restrict__ beta,
                                                     float* __restrict__ out, int n, int E) {
    const int t = threadIdx.x;
    const int lane = t & 63;
    const int c = lane & 7;      // channel chunk
    const int grp = lane >> 3;   // edge group
    const int node = blockIdx.x * 4 + (t >> 6);
    if (node >= n) return;
    int beg = starts[node];
    int end = (node == n - 1) ? E : starts[node + 1];
    beg = __builtin_amdgcn_readfirstlane(beg);
    end = __builtin_amdgcn_readfirstlane(end);

    float a0 = 0, a1 = 0, a2 = 0, a3 = 0, a4 = 0, a5 = 0, a6 = 0, a7 = 0;

    int k = beg + grp;
    for (; k + 8 < end; k += 16) {
        int s0 = eidx[k].x;
        int s1 = eidx[k + 8].x;
        uint4 r0 = *reinterpret_cast<const uint4*>(&T[(long)s0 * 64 + c * 8]);
        uint4 r1 = *reinterpret_cast<const uint4*>(&T[(long)s1 * 64 + c * 8]);
        a0 += bflo(r0.x); a1 += bfhi(r0.x); a2 += bflo(r0.y); a3 += bfhi(r0.y);
        a4 += bflo(r0.z); a5 += bfhi(r0.z); a6 += bflo(r0.w); a7 += bfhi(r0.w);
        a0 += bflo(r1.x); a1 += bfhi(r1.x); a2 += bflo(r1.y); a3 += bfhi(r1.y);
        a4 += bflo(r1.z); a5 += bfhi(r1.z); a6 += bflo(r1.w); a7 += bfhi(r1.w);
    }
    if (k < end) {
        int s = eidx[k].x;
        uint4 r = *reinterpret_cast<const uint4*>(&T[(long)s * 64 + c * 8]);
        a0 += bflo(r.x); a1 += bfhi(r.x); a2 += bflo(r.y); a3 += bfhi(r.y);
        a4 += bflo(r.z); a5 += bfhi(r.z); a6 += bflo(r.w); a7 += bfhi(r.w);
    }

    // reduce across the 8 edge groups (lane bits 3..5)
#pragma unroll
    for (int off = 8; off <= 32; off <<= 1) {
        a0 += __shfl_xor(a0, off, 64); a1 += __shfl_xor(a1, off, 64);
        a2 += __shfl_xor(a2, off, 64); a3 += __shfl_xor(a3, off, 64);
        a4 += __shfl_xor(a4, off, 64); a5 += __shfl_xor(a5, off, 64);
        a6 += __shfl_xor(a6, off, 64); a7 += __shfl_xor(a7, off, 64);
    }

    // self loop + bias: out = dinv[v]*(sum + T'[v]) + b
    const float di = dinv[node];
    uint4 rs = *reinterpret_cast<const uint4*>(&T[(long)node * 64 + c * 8]);
    float4 bb0 = *reinterpret_cast<const float4*>(&b[c * 8]);
    float4 bb1 = *reinterpret_cast<const float4*>(&b[c * 8 + 4]);
    float v0 = di * (a0 + bflo(rs.x)) + bb0.x;
    float v1 = di * (a1 + bfhi(rs.x)) + bb0.y;
    float v2 = di * (a2 + bflo(rs.y)) + bb0.z;
    float v3 = di * (a3 + bfhi(rs.y)) + bb0.w;
    float v4 = di * (a4 + bflo(rs.z)) + bb1.x;
    float v5 = di * (a5 + bfhi(rs.z)) + bb1.y;
    float v6 = di * (a6 + bflo(rs.w)) + bb1.z;
    float v7 = di * (a7 + bfhi(rs.w)) + bb1.w;

    if (MODE == 0) {
        v0 = fmaxf(v0, 0.f); v1 = fmaxf(v1, 0.f); v2 = fmaxf(v2, 0.f); v3 = fmaxf(v3, 0.f);
        v4 = fmaxf(v4, 0.f); v5 = fmaxf(v5, 0.f); v6 = fmaxf(v6, 0.f); v7 = fmaxf(v7, 0.f);
        float s = v0 + v1 + v2 + v3 + v4 + v5 + v6 + v7;
#pragma unroll
        for (int off = 1; off <= 4; off <<= 1) s += __shfl_xor(s, off, 64);
        float mu = s * (1.0f / 64.0f);
        float d0 = v0 - mu, d1 = v1 - mu, d2 = v2 - mu, d3 = v3 - mu;
        float d4 = v4 - mu, d5 = v5 - mu, d6 = v6 - mu, d7 = v7 - mu;
        float q = d0*d0 + d1*d1 + d2*d2 + d3*d3 + d4*d4 + d5*d5 + d6*d6 + d7*d7;
#pragma unroll
        for (int off = 1; off <= 4; off <<= 1) q += __shfl_xor(q, off, 64);
        float inv = rsqrtf(q * (1.0f / 64.0f) + LN_EPS);
        float4 gg0 = *reinterpret_cast<const float4*>(&g[c * 8]);
        float4 gg1 = *reinterpret_cast<const float4*>(&g[c * 8 + 4]);
        float4 be0 = *reinterpret_cast<const float4*>(&beta[c * 8]);
        float4 be1 = *reinterpret_cast<const float4*>(&beta[c * 8 + 4]);
        if (grp == 0) {
            float4 o0 = make_float4(d0 * inv * gg0.x + be0.x, d1 * inv * gg0.y + be0.y,
                                    d2 * inv * gg0.z + be0.z, d3 * inv * gg0.w + be0.w);
            float4 o1 = make_float4(d4 * inv * gg1.x + be1.x, d5 * inv * gg1.y + be1.y,
                                    d6 * inv * gg1.z + be1.z, d7 * inv * gg1.w + be1.w);
            *reinterpret_cast<float4*>(&out[(long)node * 64 + c * 8]) = o0;
            *reinterpret_cast<float4*>(&out[(long)node * 64 + c * 8 + 4]) = o1;
        }
    } else {
        if (grp == 0) {
            *reinterpret_cast<float4*>(&out[(long)node * 64 + c * 8]) = make_float4(v0, v1, v2, v3);
            *reinterpret_cast<float4*>(&out[(long)node * 64 + c * 8 + 4]) = make_float4(v4, v5, v6, v7);
        }
    }
}

extern "C" void kernel_launch(void* const* d_in, const int* in_sizes, int n_in,
                              void* d_out, int out_size, void* d_ws, size_t ws_size,
                              hipStream_t stream) {
    const float* x    = (const float*)d_in[0];
    const int*   ei   = (const int*)d_in[1];
    const float* W_in = (const float*)d_in[2];
    const float* b_in = (const float*)d_in[3];
    const float* g_in = (const float*)d_in[4];
    const float* be_in= (const float*)d_in[5];
    const float* W_h  = (const float*)d_in[6];
    const float* b_h  = (const float*)d_in[7];
    const float* g_h  = (const float*)d_in[8];
    const float* be_h = (const float*)d_in[9];
    const float* W_out= (const float*)d_in[10];
    const float* b_out= (const float*)d_in[11];
    float* out = (float*)d_out;

    const int n = in_sizes[0] / 128;   // 100000
    const int E = in_sizes[1] / 2;     // 1600000
    const int* src = ei;
    const int* dst = ei + E;

    // workspace: eidx[E int2] | dinv[NP f] | degi[NP] | starts[NP] | cursor[NP] | bsum[1024] | T[NP*64 u16] | H[NP*64 f]
    const long NP = ((long)n + 127) & ~127L;
    int2*  eidx   = (int2*)d_ws;
    float* dinv   = (float*)(eidx + E);
    int*   degi   = (int*)(dinv + NP);
    int*   starts = degi + NP;
    int*   cursor = starts + NP;
    int*   bsum   = cursor + NP;
    unsigned short* T = (unsigned short*)(bsum + 1024);
    float* H      = (float*)(T + NP * 64);

    const int nb = (n + 1023) / 1024;  // 98 (<=128 required by scan_bsum)

    // ---- CSR-transpose build (shared by all 3 layers) ----
    hipMemsetAsync(degi, 0, (size_t)n * sizeof(int), stream);
    deg_kernel<<<2048, 256, 0, stream>>>(dst, E, degi);
    dinv_kernel<<<(n + 255) / 256, 256, 0, stream>>>(degi, dinv, n);
    scan_block_kernel<<<nb, 256, 0, stream>>>(degi, n, starts, bsum);
    scan_bsum_kernel<<<1, 128, 0, stream>>>(bsum, nb);
    add_off_kernel<<<nb, 256, 0, stream>>>(starts, bsum, cursor, n);
    fill_kernel<<<2048, 256, 0, stream>>>(src, dst, cursor, eidx, E);

    const int ggrid = (n + 3) / 4;

    // ---- layer 1 ----
    gemm_kernel<128><<<(n + 63) / 64, 256, 0, stream>>>(x, W_in, dinv, T, n);
    gather_kernel<0><<<ggrid, 256, 0, stream>>>(T, starts, eidx, dinv, b_in, g_in, be_in, H, n, E);

    // ---- layer 2 ----
    gemm_kernel<64><<<(n + 63) / 64, 256, 0, stream>>>(H, W_h, dinv, T, n);
    gather_kernel<0><<<ggrid, 256, 0, stream>>>(T, starts, eidx, dinv, b_h, g_h, be_h, H, n, E);

    // ---- layer 3 (no ReLU/LN, straight to output) ----
    gemm_kernel<64><<<(n + 63) / 64, 256, 0, stream>>>(H, W_out, dinv, T, n);
    gather_kernel<1><<<ggrid, 256, 0, stream>>>(T, starts, eidx, dinv, b_out, nullptr, nullptr, out, n, E);
}

// Round 6
// 272.923 us; speedup vs baseline: 1.7360x; 1.5947x over previous
//
#include <hip/hip_runtime.h>

// GraphEncoder: 3x (GCNConv -> [ReLU -> LayerNorm]) on N=100000 nodes, E=1.6M edges.
// Round 6: CSR build rewritten as 2-level bucket sort to kill cross-XCD dirty-line
// ping-pong (fill_kernel was contention-bound at 138us with 8x write amplification).
//   hist(256-bin LDS partials) -> scan256 -> bin(chunk->bucket streams, LDS-staged
//   coalesced bursts) -> build(per-bucket: deg/dinv/starts via LDS, L2-local fine scatter).
// No contended global atomics anywhere except bucket cursors (100K on 256 ints).

constexpr float LN_EPS = 1e-5f;
constexpr int BUCKETS = 256;
constexpr int CHUNK = 4096;

// ---- bf16 helpers (RNE) ----
__device__ inline unsigned bf1(float x) {
    unsigned u = __float_as_uint(x);
    return (u + 0x7FFFu + ((u >> 16) & 1u)) >> 16;
}
__device__ inline unsigned bfpack(float lo, float hi) { return bf1(lo) | (bf1(hi) << 16); }
__device__ inline float bflo(unsigned r) { return __uint_as_float(r << 16); }
__device__ inline float bfhi(unsigned r) { return __uint_as_float(r & 0xFFFF0000u); }

// ---------------- hist: per-block LDS histogram of dst buckets -> partial[block][bin] ----------------
__global__ __launch_bounds__(256) void hist_kernel(const int* __restrict__ dst, int E, int bpb,
                                                   int* __restrict__ partial) {
    __shared__ int h[BUCKETS];
    const int t = threadIdx.x;
    h[t] = 0;
    __syncthreads();
    int i = blockIdx.x * blockDim.x + t;
    const int stride = gridDim.x * blockDim.x;
    for (; i < E; i += stride) atomicAdd(&h[dst[i] / bpb], 1);
    __syncthreads();
    partial[blockIdx.x * BUCKETS + t] = h[t];
}

// ---------------- scan256: column-sum partials, exclusive scan -> ebase, gcur ----------------
__global__ __launch_bounds__(256) void scan256_kernel(const int* __restrict__ partial, int nblk,
                                                      int* __restrict__ ebase, int* __restrict__ gcur) {
    __shared__ int wsum[4];
    const int t = threadIdx.x, lane = t & 63, w = t >> 6;
    int s0 = 0, s1 = 0, s2 = 0, s3 = 0;
    int i = 0;
    for (; i + 4 <= nblk; i += 4) {
        s0 += partial[(i + 0) * BUCKETS + t];
        s1 += partial[(i + 1) * BUCKETS + t];
        s2 += partial[(i + 2) * BUCKETS + t];
        s3 += partial[(i + 3) * BUCKETS + t];
    }
    for (; i < nblk; ++i) s0 += partial[i * BUCKETS + t];
    int v = s0 + s1 + s2 + s3;
    int inc = v;
#pragma unroll
    for (int off = 1; off < 64; off <<= 1) {
        int u = __shfl_up(inc, off, 64);
        if (lane >= off) inc += u;
    }
    if (lane == 63) wsum[w] = inc;
    __syncthreads();
    int woff = 0;
#pragma unroll
    for (int j = 0; j < 4; ++j)
        if (j < w) woff += wsum[j];
    int ex = woff + inc - v;
    ebase[t] = ex;
    gcur[t] = ex;
}

// ---------------- bin (pass 1): chunk -> LDS-grouped -> coalesced bursts to bucket streams ----------------
__global__ __launch_bounds__(512) void bin_kernel(const int* __restrict__ src,
                                                  const int* __restrict__ dst, int E, int bpb,
                                                  int* __restrict__ gcur,
                                                  uint2* __restrict__ binned) {
    __shared__ uint2 stag[CHUNK];
    __shared__ int cnt[BUCKETS], lstart[BUCKETS], loff[BUCKETS], gbase[BUCKETS];
    __shared__ int wsum[4];
    const int t = threadIdx.x;
    const int cb = blockIdx.x * CHUNK;
    const int csize = min(CHUNK, E - cb);

    if (t < BUCKETS) cnt[t] = 0;
    __syncthreads();

    // phase A: load edges to regs, count buckets
    int sr[8], dr[8];
#pragma unroll
    for (int j = 0; j < 8; ++j) {
        int i = t + j * 512;
        if (i < csize) {
            sr[j] = src[cb + i];
            dr[j] = dst[cb + i];
            atomicAdd(&cnt[dr[j] / bpb], 1);
        }
    }
    __syncthreads();

    // phase B: exclusive scan of cnt -> lstart, loff
    if (t < BUCKETS) {
        const int lane = t & 63, w = t >> 6;
        int v = cnt[t];
        int inc = v;
#pragma unroll
        for (int off = 1; off < 64; off <<= 1) {
            int u = __shfl_up(inc, off, 64);
            if (lane >= off) inc += u;
        }
        if (lane == 63) wsum[w] = inc;
        __syncthreads();
        int woff = 0;
#pragma unroll
        for (int j = 0; j < 4; ++j)
            if (j < w) woff += wsum[j];
        int ex = woff + inc - v;
        lstart[t] = ex;
        loff[t] = ex;
    } else {
        __syncthreads();
    }
    __syncthreads();

    // phase C: place into staging grouped by bucket
#pragma unroll
    for (int j = 0; j < 8; ++j) {
        int i = t + j * 512;
        if (i < csize) {
            int b = dr[j] / bpb;
            int pos = atomicAdd(&loff[b], 1);
            stag[pos] = make_uint2((unsigned)sr[j], (unsigned)dr[j]);
        }
    }
    __syncthreads();

    // phase D: reserve global ranges
    if (t < BUCKETS && cnt[t] > 0) gbase[t] = atomicAdd(&gcur[t], cnt[t]);
    __syncthreads();

    // phase E: burst-copy runs (consecutive slots in a bucket -> consecutive global)
    for (int s = t; s < csize; s += 512) {
        uint2 p = stag[s];
        int b = (int)p.y / bpb;
        binned[gbase[b] + (s - lstart[b])] = p;
    }
}

// ---------------- build (pass 2): per-bucket deg/dinv/starts + L2-local fine scatter ----------------
__global__ __launch_bounds__(256) void build_kernel(const uint2* __restrict__ binned,
                                                    const int* __restrict__ ebase, int E, int bpb, int n,
                                                    int* __restrict__ starts,
                                                    float* __restrict__ dinv,
                                                    int* __restrict__ eidx) {
    __shared__ int degL[512];
    __shared__ int posL[512];
    __shared__ int wsum[4];
    const int t = threadIdx.x, lane = t & 63, w = t >> 6;
    const int b = blockIdx.x;
    const int nb0 = b * bpb;
    const int nloc = min(bpb, n - nb0);
    if (nloc <= 0) return;
    const int gs = ebase[b];
    const int ge = (b == BUCKETS - 1) ? E : ebase[b + 1];

    degL[t] = 0;
    degL[t + 256] = 0;
    __syncthreads();

    // local degree histogram
    for (int k = gs + t; k < ge; k += 256) {
        uint2 p = binned[k];
        atomicAdd(&degL[(int)p.y - nb0], 1);
    }
    __syncthreads();

    // exclusive scan of degL[0..512) -> posL (2 elems per thread)
    int v0 = degL[2 * t], v1 = degL[2 * t + 1];
    int s2 = v0 + v1;
    int inc = s2;
#pragma unroll
    for (int off = 1; off < 64; off <<= 1) {
        int u = __shfl_up(inc, off, 64);
        if (lane >= off) inc += u;
    }
    if (lane == 63) wsum[w] = inc;
    __syncthreads();
    int woff = 0;
#pragma unroll
    for (int j = 0; j < 4; ++j)
        if (j < w) woff += wsum[j];
    int ex = woff + inc - s2;
    posL[2 * t] = ex;
    posL[2 * t + 1] = ex + v0;
    __syncthreads();

    // write global starts + dinv
    for (int i = t; i < nloc; i += 256) {
        starts[nb0 + i] = gs + posL[i];
        dinv[nb0 + i] = rsqrtf((float)degL[i] + 1.0f);
    }
    __syncthreads();

    // fine scatter (posL doubles as cursor; eidx window is block-private -> L2-local)
    for (int k = gs + t; k < ge; k += 256) {
        uint2 p = binned[k];
        int pos = atomicAdd(&posL[(int)p.y - nb0], 1);
        eidx[gs + pos] = (int)p.x;
    }
}

// ---------------- dense GEMM: T[n x 64] = bf16( (X[n x DIN] @ W[DIN x 64]) * dinv[row] ) ----------------
template <int DIN>
__global__ __launch_bounds__(256) void gemm_kernel(const float* __restrict__ X,
                                                   const float* __restrict__ W,
                                                   const float* __restrict__ dinv,
                                                   unsigned short* __restrict__ T, int n) {
    __shared__ float xs[64][33];
    __shared__ float ws[32][64];
    const int t  = threadIdx.x;
    const int n0 = blockIdx.x * 64;
    const int tc = t & 15;
    const int tr = t >> 4;

    float acc[4][4] = {};

    for (int k0 = 0; k0 < DIN; k0 += 32) {
        for (int l = t; l < 512; l += 256) {
            int r = l >> 3;
            int q = (l & 7) << 2;
            int row = n0 + r;
            float4 v = make_float4(0.f, 0.f, 0.f, 0.f);
            if (row < n) v = *reinterpret_cast<const float4*>(&X[(long)row * DIN + k0 + q]);
            xs[r][q + 0] = v.x; xs[r][q + 1] = v.y; xs[r][q + 2] = v.z; xs[r][q + 3] = v.w;
        }
        for (int l = t; l < 512; l += 256) {
            int r = l >> 4;
            int q = (l & 15) << 2;
            float4 v = *reinterpret_cast<const float4*>(&W[(long)(k0 + r) * 64 + q]);
            *reinterpret_cast<float4*>(&ws[r][q]) = v;
        }
        __syncthreads();
#pragma unroll
        for (int k = 0; k < 32; ++k) {
            float4 wv = *reinterpret_cast<const float4*>(&ws[k][tc * 4]);
#pragma unroll
            for (int j = 0; j < 4; ++j) {
                float xv = xs[tr * 4 + j][k];
                acc[j][0] += xv * wv.x;
                acc[j][1] += xv * wv.y;
                acc[j][2] += xv * wv.z;
                acc[j][3] += xv * wv.w;
            }
        }
        __syncthreads();
    }

    for (int j = 0; j < 4; ++j) {
        int row = n0 + tr * 4 + j;
        if (row < n) {
            float di = dinv[row];
            uint2 p;
            p.x = bfpack(acc[j][0] * di, acc[j][1] * di);
            p.y = bfpack(acc[j][2] * di, acc[j][3] * di);
            *reinterpret_cast<uint2*>(&T[(long)row * 64 + tc * 4]) = p;
        }
    }
}

// ---------------- fused gather + self-loop + bias (+ ReLU + LayerNorm) ----------------
// One wave per node. bf16 row = 128B. Lane = grp*8 + c: grp in [0,8) = edge group,
// c in [0,8) = channel chunk. One row-load instr gathers 8 edges; unroll x2 = 16 in flight.
template <int MODE>
__global__ __launch_bounds__(256) void gather_kernel(const unsigned short* __restrict__ T,
                                                     const int* __restrict__ starts,
                                                     const int* __restrict__ eidx,
                                                     const float* __restrict__ dinv,
                                                     const float* __restrict__ b,
                                                     const float* __restrict__ g,
                                                     const float* __restrict__ beta,
                                                     float* __restrict__ out, int n, int E) {
    const int t = threadIdx.x;
    const int lane = t & 63;
    const int c = lane & 7;      // channel chunk
    const int grp = lane >> 3;   // edge group
    const int node = blockIdx.x * 4 + (t >> 6);
    if (node >= n) return;
    int beg = starts[node];
    int end = (node == n - 1) ? E : starts[node + 1];
    beg = __builtin_amdgcn_readfirstlane(beg);
    end = __builtin_amdgcn_readfirstlane(end);

    float a0 = 0, a1 = 0, a2 = 0, a3 = 0, a4 = 0, a5 = 0, a6 = 0, a7 = 0;

    int k = beg + grp;
    for (; k + 8 < end; k += 16) {
        int s0 = eidx[k];
        int s1 = eidx[k + 8];
        uint4 r0 = *reinterpret_cast<const uint4*>(&T[(long)s0 * 64 + c * 8]);
        uint4 r1 = *reinterpret_cast<const uint4*>(&T[(long)s1 * 64 + c * 8]);
        a0 += bflo(r0.x); a1 += bfhi(r0.x); a2 += bflo(r0.y); a3 += bfhi(r0.y);
        a4 += bflo(r0.z); a5 += bfhi(r0.z); a6 += bflo(r0.w); a7 += bfhi(r0.w);
        a0 += bflo(r1.x); a1 += bfhi(r1.x); a2 += bflo(r1.y); a3 += bfhi(r1.y);
        a4 += bflo(r1.z); a5 += bfhi(r1.z); a6 += bflo(r1.w); a7 += bfhi(r1.w);
    }
    if (k < end) {
        int s = eidx[k];
        uint4 r = *reinterpret_cast<const uint4*>(&T[(long)s * 64 + c * 8]);
        a0 += bflo(r.x); a1 += bfhi(r.x); a2 += bflo(r.y); a3 += bfhi(r.y);
        a4 += bflo(r.z); a5 += bfhi(r.z); a6 += bflo(r.w); a7 += bfhi(r.w);
    }

#pragma unroll
    for (int off = 8; off <= 32; off <<= 1) {
        a0 += __shfl_xor(a0, off, 64); a1 += __shfl_xor(a1, off, 64);
        a2 += __shfl_xor(a2, off, 64); a3 += __shfl_xor(a3, off, 64);
        a4 += __shfl_xor(a4, off, 64); a5 += __shfl_xor(a5, off, 64);
        a6 += __shfl_xor(a6, off, 64); a7 += __shfl_xor(a7, off, 64);
    }

    const float di = dinv[node];
    uint4 rs = *reinterpret_cast<const uint4*>(&T[(long)node * 64 + c * 8]);
    float4 bb0 = *reinterpret_cast<const float4*>(&b[c * 8]);
    float4 bb1 = *reinterpret_cast<const float4*>(&b[c * 8 + 4]);
    float v0 = di * (a0 + bflo(rs.x)) + bb0.x;
    float v1 = di * (a1 + bfhi(rs.x)) + bb0.y;
    float v2 = di * (a2 + bflo(rs.y)) + bb0.z;
    float v3 = di * (a3 + bfhi(rs.y)) + bb0.w;
    float v4 = di * (a4 + bflo(rs.z)) + bb1.x;
    float v5 = di * (a5 + bfhi(rs.z)) + bb1.y;
    float v6 = di * (a6 + bflo(rs.w)) + bb1.z;
    float v7 = di * (a7 + bfhi(rs.w)) + bb1.w;

    if (MODE == 0) {
        v0 = fmaxf(v0, 0.f); v1 = fmaxf(v1, 0.f); v2 = fmaxf(v2, 0.f); v3 = fmaxf(v3, 0.f);
        v4 = fmaxf(v4, 0.f); v5 = fmaxf(v5, 0.f); v6 = fmaxf(v6, 0.f); v7 = fmaxf(v7, 0.f);
        float s = v0 + v1 + v2 + v3 + v4 + v5 + v6 + v7;
#pragma unroll
        for (int off = 1; off <= 4; off <<= 1) s += __shfl_xor(s, off, 64);
        float mu = s * (1.0f / 64.0f);
        float d0 = v0 - mu, d1 = v1 - mu, d2 = v2 - mu, d3 = v3 - mu;
        float d4 = v4 - mu, d5 = v5 - mu, d6 = v6 - mu, d7 = v7 - mu;
        float q = d0*d0 + d1*d1 + d2*d2 + d3*d3 + d4*d4 + d5*d5 + d6*d6 + d7*d7;
#pragma unroll
        for (int off = 1; off <= 4; off <<= 1) q += __shfl_xor(q, off, 64);
        float inv = rsqrtf(q * (1.0f / 64.0f) + LN_EPS);
        float4 gg0 = *reinterpret_cast<const float4*>(&g[c * 8]);
        float4 gg1 = *reinterpret_cast<const float4*>(&g[c * 8 + 4]);
        float4 be0 = *reinterpret_cast<const float4*>(&beta[c * 8]);
        float4 be1 = *reinterpret_cast<const float4*>(&beta[c * 8 + 4]);
        if (grp == 0) {
            float4 o0 = make_float4(d0 * inv * gg0.x + be0.x, d1 * inv * gg0.y + be0.y,
                                    d2 * inv * gg0.z + be0.z, d3 * inv * gg0.w + be0.w);
            float4 o1 = make_float4(d4 * inv * gg1.x + be1.x, d5 * inv * gg1.y + be1.y,
                                    d6 * inv * gg1.z + be1.z, d7 * inv * gg1.w + be1.w);
            *reinterpret_cast<float4*>(&out[(long)node * 64 + c * 8]) = o0;
            *reinterpret_cast<float4*>(&out[(long)node * 64 + c * 8 + 4]) = o1;
        }
    } else {
        if (grp == 0) {
            *reinterpret_cast<float4*>(&out[(long)node * 64 + c * 8]) = make_float4(v0, v1, v2, v3);
            *reinterpret_cast<float4*>(&out[(long)node * 64 + c * 8 + 4]) = make_float4(v4, v5, v6, v7);
        }
    }
}

extern "C" void kernel_launch(void* const* d_in, const int* in_sizes, int n_in,
                              void* d_out, int out_size, void* d_ws, size_t ws_size,
                              hipStream_t stream) {
    const float* x    = (const float*)d_in[0];
    const int*   ei   = (const int*)d_in[1];
    const float* W_in = (const float*)d_in[2];
    const float* b_in = (const float*)d_in[3];
    const float* g_in = (const float*)d_in[4];
    const float* be_in= (const float*)d_in[5];
    const float* W_h  = (const float*)d_in[6];
    const float* b_h  = (const float*)d_in[7];
    const float* g_h  = (const float*)d_in[8];
    const float* be_h = (const float*)d_in[9];
    const float* W_out= (const float*)d_in[10];
    const float* b_out= (const float*)d_in[11];
    float* out = (float*)d_out;

    const int n = in_sizes[0] / 128;   // 100000
    const int E = in_sizes[1] / 2;     // 1600000
    const int* src = ei;
    const int* dst = ei + E;

    const int bpb = (n + BUCKETS - 1) / BUCKETS;  // nodes per bucket (391)
    const int HIST_BLOCKS = 256;

    // workspace: binned[E uint2] | eidx[E i32] | partial[HB*256] | ebase[256] | gcur[256]
    //            | dinv[NP f] | starts[NP i] | T[NP*64 u16] | H[NP*64 f]
    const long NP = ((long)n + 127) & ~127L;
    uint2* binned = (uint2*)d_ws;
    int*   eidx   = (int*)(binned + E);
    int*   partial= eidx + E;
    int*   ebase  = partial + HIST_BLOCKS * BUCKETS;
    int*   gcur   = ebase + BUCKETS;
    float* dinv   = (float*)(gcur + BUCKETS);
    int*   starts = (int*)(dinv + NP);
    unsigned short* T = (unsigned short*)(starts + NP);
    float* H      = (float*)(T + NP * 64);

    // ---- CSR-transpose build via 2-level bucket sort ----
    hist_kernel<<<HIST_BLOCKS, 256, 0, stream>>>(dst, E, bpb, partial);
    scan256_kernel<<<1, 256, 0, stream>>>(partial, HIST_BLOCKS, ebase, gcur);
    bin_kernel<<<(E + CHUNK - 1) / CHUNK, 512, 0, stream>>>(src, dst, E, bpb, gcur, binned);
    build_kernel<<<BUCKETS, 256, 0, stream>>>(binned, ebase, E, bpb, n, starts, dinv, eidx);

    const int ggrid = (n + 3) / 4;

    // ---- layer 1 ----
    gemm_kernel<128><<<(n + 63) / 64, 256, 0, stream>>>(x, W_in, dinv, T, n);
    gather_kernel<0><<<ggrid, 256, 0, stream>>>(T, starts, eidx, dinv, b_in, g_in, be_in, H, n, E);

    // ---- layer 2 ----
    gemm_kernel<64><<<(n + 63) / 64, 256, 0, stream>>>(H, W_h, dinv, T, n);
    gather_kernel<0><<<ggrid, 256, 0, stream>>>(T, starts, eidx, dinv, b_h, g_h, be_h, H, n, E);

    // ---- layer 3 (no ReLU/LN, straight to output) ----
    gemm_kernel<64><<<(n + 63) / 64, 256, 0, stream>>>(H, W_out, dinv, T, n);
    gather_kernel<1><<<ggrid, 256, 0, stream>>>(T, starts, eidx, dinv, b_out, nullptr, nullptr, out, n, E);
}

// Round 7
// 270.578 us; speedup vs baseline: 1.7510x; 1.0087x over previous
//
#include <hip/hip_runtime.h>

// GraphEncoder: 3x (GCNConv -> [ReLU -> LayerNorm]) on N=100000 nodes, E=1.6M edges.
// Round 7: gather addressing in 32-bit (eidx stores byte offsets src*128; all loads
// become SGPR-base + 32-bit voffset) to cut the 64-bit addr-math VALU (VALUBusy 65%).
// CSR build via 2-level bucket sort (round 6, kills cross-XCD dirty-line ping-pong).

constexpr float LN_EPS = 1e-5f;
constexpr int BUCKETS = 256;
constexpr int CHUNK = 4096;

// ---- bf16 helpers (RNE) ----
__device__ inline unsigned bf1(float x) {
    unsigned u = __float_as_uint(x);
    return (u + 0x7FFFu + ((u >> 16) & 1u)) >> 16;
}
__device__ inline unsigned bfpack(float lo, float hi) { return bf1(lo) | (bf1(hi) << 16); }
__device__ inline float bflo(unsigned r) { return __uint_as_float(r << 16); }
__device__ inline float bfhi(unsigned r) { return __uint_as_float(r & 0xFFFF0000u); }

// ---------------- hist: per-block LDS histogram of dst buckets -> partial[block][bin] ----------------
__global__ __launch_bounds__(256) void hist_kernel(const int* __restrict__ dst, int E, int bpb,
                                                   int* __restrict__ partial) {
    __shared__ int h[BUCKETS];
    const int t = threadIdx.x;
    h[t] = 0;
    __syncthreads();
    int i = blockIdx.x * blockDim.x + t;
    const int stride = gridDim.x * blockDim.x;
    for (; i < E; i += stride) atomicAdd(&h[dst[i] / bpb], 1);
    __syncthreads();
    partial[blockIdx.x * BUCKETS + t] = h[t];
}

// ---------------- scan256: column-sum partials, exclusive scan -> ebase, gcur ----------------
__global__ __launch_bounds__(256) void scan256_kernel(const int* __restrict__ partial, int nblk,
                                                      int* __restrict__ ebase, int* __restrict__ gcur) {
    __shared__ int wsum[4];
    const int t = threadIdx.x, lane = t & 63, w = t >> 6;
    int s0 = 0, s1 = 0, s2 = 0, s3 = 0;
    int i = 0;
    for (; i + 4 <= nblk; i += 4) {
        s0 += partial[(i + 0) * BUCKETS + t];
        s1 += partial[(i + 1) * BUCKETS + t];
        s2 += partial[(i + 2) * BUCKETS + t];
        s3 += partial[(i + 3) * BUCKETS + t];
    }
    for (; i < nblk; ++i) s0 += partial[i * BUCKETS + t];
    int v = s0 + s1 + s2 + s3;
    int inc = v;
#pragma unroll
    for (int off = 1; off < 64; off <<= 1) {
        int u = __shfl_up(inc, off, 64);
        if (lane >= off) inc += u;
    }
    if (lane == 63) wsum[w] = inc;
    __syncthreads();
    int woff = 0;
#pragma unroll
    for (int j = 0; j < 4; ++j)
        if (j < w) woff += wsum[j];
    int ex = woff + inc - v;
    ebase[t] = ex;
    gcur[t] = ex;
}

// ---------------- bin (pass 1): chunk -> LDS-grouped -> coalesced bursts to bucket streams ----------------
__global__ __launch_bounds__(512) void bin_kernel(const int* __restrict__ src,
                                                  const int* __restrict__ dst, int E, int bpb,
                                                  int* __restrict__ gcur,
                                                  uint2* __restrict__ binned) {
    __shared__ uint2 stag[CHUNK];
    __shared__ int cnt[BUCKETS], lstart[BUCKETS], loff[BUCKETS], gbase[BUCKETS];
    __shared__ int wsum[4];
    const int t = threadIdx.x;
    const int cb = blockIdx.x * CHUNK;
    const int csize = min(CHUNK, E - cb);

    if (t < BUCKETS) cnt[t] = 0;
    __syncthreads();

    // phase A: load edges to regs, count buckets
    int sr[8], dr[8];
#pragma unroll
    for (int j = 0; j < 8; ++j) {
        int i = t + j * 512;
        if (i < csize) {
            sr[j] = src[cb + i];
            dr[j] = dst[cb + i];
            atomicAdd(&cnt[dr[j] / bpb], 1);
        }
    }
    __syncthreads();

    // phase B: exclusive scan of cnt -> lstart, loff
    if (t < BUCKETS) {
        const int lane = t & 63, w = t >> 6;
        int v = cnt[t];
        int inc = v;
#pragma unroll
        for (int off = 1; off < 64; off <<= 1) {
            int u = __shfl_up(inc, off, 64);
            if (lane >= off) inc += u;
        }
        if (lane == 63) wsum[w] = inc;
        __syncthreads();
        int woff = 0;
#pragma unroll
        for (int j = 0; j < 4; ++j)
            if (j < w) woff += wsum[j];
        int ex = woff + inc - v;
        lstart[t] = ex;
        loff[t] = ex;
    } else {
        __syncthreads();
    }
    __syncthreads();

    // phase C: place into staging grouped by bucket
#pragma unroll
    for (int j = 0; j < 8; ++j) {
        int i = t + j * 512;
        if (i < csize) {
            int b = dr[j] / bpb;
            int pos = atomicAdd(&loff[b], 1);
            stag[pos] = make_uint2((unsigned)sr[j], (unsigned)dr[j]);
        }
    }
    __syncthreads();

    // phase D: reserve global ranges
    if (t < BUCKETS && cnt[t] > 0) gbase[t] = atomicAdd(&gcur[t], cnt[t]);
    __syncthreads();

    // phase E: burst-copy runs (consecutive slots in a bucket -> consecutive global)
    for (int s = t; s < csize; s += 512) {
        uint2 p = stag[s];
        int b = (int)p.y / bpb;
        binned[gbase[b] + (s - lstart[b])] = p;
    }
}

// ---------------- build (pass 2): per-bucket deg/dinv/starts + L2-local fine scatter ----------------
// eidx entries are BYTE OFFSETS into T (src*128) so the gather can use 32-bit addressing.
__global__ __launch_bounds__(256) void build_kernel(const uint2* __restrict__ binned,
                                                    const int* __restrict__ ebase, int E, int bpb, int n,
                                                    int* __restrict__ starts,
                                                    float* __restrict__ dinv,
                                                    int* __restrict__ eidx) {
    __shared__ int degL[512];
    __shared__ int posL[512];
    __shared__ int wsum[4];
    const int t = threadIdx.x, lane = t & 63, w = t >> 6;
    const int b = blockIdx.x;
    const int nb0 = b * bpb;
    const int nloc = min(bpb, n - nb0);
    if (nloc <= 0) return;
    const int gs = ebase[b];
    const int ge = (b == BUCKETS - 1) ? E : ebase[b + 1];

    degL[t] = 0;
    degL[t + 256] = 0;
    __syncthreads();

    // local degree histogram
    for (int k = gs + t; k < ge; k += 256) {
        uint2 p = binned[k];
        atomicAdd(&degL[(int)p.y - nb0], 1);
    }
    __syncthreads();

    // exclusive scan of degL[0..512) -> posL (2 elems per thread)
    int v0 = degL[2 * t], v1 = degL[2 * t + 1];
    int s2 = v0 + v1;
    int inc = s2;
#pragma unroll
    for (int off = 1; off < 64; off <<= 1) {
        int u = __shfl_up(inc, off, 64);
        if (lane >= off) inc += u;
    }
    if (lane == 63) wsum[w] = inc;
    __syncthreads();
    int woff = 0;
#pragma unroll
    for (int j = 0; j < 4; ++j)
        if (j < w) woff += wsum[j];
    int ex = woff + inc - s2;
    posL[2 * t] = ex;
    posL[2 * t + 1] = ex + v0;
    __syncthreads();

    // write global starts + dinv
    for (int i = t; i < nloc; i += 256) {
        starts[nb0 + i] = gs + posL[i];
        dinv[nb0 + i] = rsqrtf((float)degL[i] + 1.0f);
    }
    __syncthreads();

    // fine scatter (posL doubles as cursor; eidx window is block-private -> L2-local)
    for (int k = gs + t; k < ge; k += 256) {
        uint2 p = binned[k];
        int pos = atomicAdd(&posL[(int)p.y - nb0], 1);
        eidx[gs + pos] = (int)(p.x << 7);  // byte offset: src * 128
    }
}

// ---------------- dense GEMM: T[n x 64] = bf16( (X[n x DIN] @ W[DIN x 64]) * dinv[row] ) ----------------
template <int DIN>
__global__ __launch_bounds__(256) void gemm_kernel(const float* __restrict__ X,
                                                   const float* __restrict__ W,
                                                   const float* __restrict__ dinv,
                                                   unsigned short* __restrict__ T, int n) {
    __shared__ float xs[64][33];
    __shared__ float ws[32][64];
    const int t  = threadIdx.x;
    const int n0 = blockIdx.x * 64;
    const int tc = t & 15;
    const int tr = t >> 4;

    float acc[4][4] = {};

    for (int k0 = 0; k0 < DIN; k0 += 32) {
        for (int l = t; l < 512; l += 256) {
            int r = l >> 3;
            int q = (l & 7) << 2;
            int row = n0 + r;
            float4 v = make_float4(0.f, 0.f, 0.f, 0.f);
            if (row < n) v = *reinterpret_cast<const float4*>(&X[(long)row * DIN + k0 + q]);
            xs[r][q + 0] = v.x; xs[r][q + 1] = v.y; xs[r][q + 2] = v.z; xs[r][q + 3] = v.w;
        }
        for (int l = t; l < 512; l += 256) {
            int r = l >> 4;
            int q = (l & 15) << 2;
            float4 v = *reinterpret_cast<const float4*>(&W[(long)(k0 + r) * 64 + q]);
            *reinterpret_cast<float4*>(&ws[r][q]) = v;
        }
        __syncthreads();
#pragma unroll
        for (int k = 0; k < 32; ++k) {
            float4 wv = *reinterpret_cast<const float4*>(&ws[k][tc * 4]);
#pragma unroll
            for (int j = 0; j < 4; ++j) {
                float xv = xs[tr * 4 + j][k];
                acc[j][0] += xv * wv.x;
                acc[j][1] += xv * wv.y;
                acc[j][2] += xv * wv.z;
                acc[j][3] += xv * wv.w;
            }
        }
        __syncthreads();
    }

    for (int j = 0; j < 4; ++j) {
        int row = n0 + tr * 4 + j;
        if (row < n) {
            float di = dinv[row];
            uint2 p;
            p.x = bfpack(acc[j][0] * di, acc[j][1] * di);
            p.y = bfpack(acc[j][2] * di, acc[j][3] * di);
            *reinterpret_cast<uint2*>(&T[(long)row * 64 + tc * 4]) = p;
        }
    }
}

// ---------------- fused gather + self-loop + bias (+ ReLU + LayerNorm) ----------------
// One wave per node. bf16 row = 128B. Lane = grp*8 + c: grp in [0,8) = edge group,
// c in [0,8) = channel chunk. One row-load instr gathers 8 edges; unroll x2 = 16 in flight.
// All gather addresses are uniform-base + 32-bit voffset (eidx holds byte offsets).
template <int MODE>
__global__ __launch_bounds__(256) void gather_kernel(const unsigned short* __restrict__ Tp,
                                                     const int* __restrict__ starts,
                                                     const int* __restrict__ eidx,
                                                     const float* __restrict__ dinv,
                                                     const float* __restrict__ b,
                                                     const float* __restrict__ g,
                                                     const float* __restrict__ beta,
                                                     float* __restrict__ out, int n, int E) {
    const char* __restrict__ Tb = (const char*)Tp;
    const int t = threadIdx.x;
    const int lane = t & 63;
    const int c = lane & 7;      // channel chunk
    const int grp = lane >> 3;   // edge group
    const unsigned c16 = (unsigned)c * 16u;
    const int node = blockIdx.x * 4 + (t >> 6);
    if (node >= n) return;
    int beg = starts[node];
    int end = (node == n - 1) ? E : starts[node + 1];
    beg = __builtin_amdgcn_readfirstlane(beg);
    end = __builtin_amdgcn_readfirstlane(end);

    float a0 = 0, a1 = 0, a2 = 0, a3 = 0, a4 = 0, a5 = 0, a6 = 0, a7 = 0;

    int k = beg + grp;
    for (; k + 8 < end; k += 16) {
        unsigned o0 = (unsigned)eidx[k] + c16;
        unsigned o1 = (unsigned)eidx[k + 8] + c16;
        uint4 r0 = *reinterpret_cast<const uint4*>(Tb + o0);
        uint4 r1 = *reinterpret_cast<const uint4*>(Tb + o1);
        a0 += bflo(r0.x); a1 += bfhi(r0.x); a2 += bflo(r0.y); a3 += bfhi(r0.y);
        a4 += bflo(r0.z); a5 += bfhi(r0.z); a6 += bflo(r0.w); a7 += bfhi(r0.w);
        a0 += bflo(r1.x); a1 += bfhi(r1.x); a2 += bflo(r1.y); a3 += bfhi(r1.y);
        a4 += bflo(r1.z); a5 += bfhi(r1.z); a6 += bflo(r1.w); a7 += bfhi(r1.w);
    }
    if (k < end) {
        unsigned o = (unsigned)eidx[k] + c16;
        uint4 r = *reinterpret_cast<const uint4*>(Tb + o);
        a0 += bflo(r.x); a1 += bfhi(r.x); a2 += bflo(r.y); a3 += bfhi(r.y);
        a4 += bflo(r.z); a5 += bfhi(r.z); a6 += bflo(r.w); a7 += bfhi(r.w);
    }

#pragma unroll
    for (int off = 8; off <= 32; off <<= 1) {
        a0 += __shfl_xor(a0, off, 64); a1 += __shfl_xor(a1, off, 64);
        a2 += __shfl_xor(a2, off, 64); a3 += __shfl_xor(a3, off, 64);
        a4 += __shfl_xor(a4, off, 64); a5 += __shfl_xor(a5, off, 64);
        a6 += __shfl_xor(a6, off, 64); a7 += __shfl_xor(a7, off, 64);
    }

    const float di = dinv[node];
    uint4 rs = *reinterpret_cast<const uint4*>(Tb + ((unsigned)node * 128u + c16));
    float4 bb0 = *reinterpret_cast<const float4*>(&b[c * 8]);
    float4 bb1 = *reinterpret_cast<const float4*>(&b[c * 8 + 4]);
    float v0 = di * (a0 + bflo(rs.x)) + bb0.x;
    float v1 = di * (a1 + bfhi(rs.x)) + bb0.y;
    float v2 = di * (a2 + bflo(rs.y)) + bb0.z;
    float v3 = di * (a3 + bfhi(rs.y)) + bb0.w;
    float v4 = di * (a4 + bflo(rs.z)) + bb1.x;
    float v5 = di * (a5 + bfhi(rs.z)) + bb1.y;
    float v6 = di * (a6 + bflo(rs.w)) + bb1.z;
    float v7 = di * (a7 + bfhi(rs.w)) + bb1.w;

    if (MODE == 0) {
        v0 = fmaxf(v0, 0.f); v1 = fmaxf(v1, 0.f); v2 = fmaxf(v2, 0.f); v3 = fmaxf(v3, 0.f);
        v4 = fmaxf(v4, 0.f); v5 = fmaxf(v5, 0.f); v6 = fmaxf(v6, 0.f); v7 = fmaxf(v7, 0.f);
        float s = v0 + v1 + v2 + v3 + v4 + v5 + v6 + v7;
#pragma unroll
        for (int off = 1; off <= 4; off <<= 1) s += __shfl_xor(s, off, 64);
        float mu = s * (1.0f / 64.0f);
        float d0 = v0 - mu, d1 = v1 - mu, d2 = v2 - mu, d3 = v3 - mu;
        float d4 = v4 - mu, d5 = v5 - mu, d6 = v6 - mu, d7 = v7 - mu;
        float q = d0*d0 + d1*d1 + d2*d2 + d3*d3 + d4*d4 + d5*d5 + d6*d6 + d7*d7;
#pragma unroll
        for (int off = 1; off <= 4; off <<= 1) q += __shfl_xor(q, off, 64);
        float inv = rsqrtf(q * (1.0f / 64.0f) + LN_EPS);
        float4 gg0 = *reinterpret_cast<const float4*>(&g[c * 8]);
        float4 gg1 = *reinterpret_cast<const float4*>(&g[c * 8 + 4]);
        float4 be0 = *reinterpret_cast<const float4*>(&beta[c * 8]);
        float4 be1 = *reinterpret_cast<const float4*>(&beta[c * 8 + 4]);
        if (grp == 0) {
            char* ob = (char*)out;
            float4 o0 = make_float4(d0 * inv * gg0.x + be0.x, d1 * inv * gg0.y + be0.y,
                                    d2 * inv * gg0.z + be0.z, d3 * inv * gg0.w + be0.w);
            float4 o1 = make_float4(d4 * inv * gg1.x + be1.x, d5 * inv * gg1.y + be1.y,
                                    d6 * inv * gg1.z + be1.z, d7 * inv * gg1.w + be1.w);
            unsigned oo = (unsigned)node * 256u + c16 * 2u;
            *reinterpret_cast<float4*>(ob + oo) = o0;
            *reinterpret_cast<float4*>(ob + oo + 16) = o1;
        }
    } else {
        if (grp == 0) {
            char* ob = (char*)out;
            unsigned oo = (unsigned)node * 256u + c16 * 2u;
            *reinterpret_cast<float4*>(ob + oo) = make_float4(v0, v1, v2, v3);
            *reinterpret_cast<float4*>(ob + oo + 16) = make_float4(v4, v5, v6, v7);
        }
    }
}

extern "C" void kernel_launch(void* const* d_in, const int* in_sizes, int n_in,
                              void* d_out, int out_size, void* d_ws, size_t ws_size,
                              hipStream_t stream) {
    const float* x    = (const float*)d_in[0];
    const int*   ei   = (const int*)d_in[1];
    const float* W_in = (const float*)d_in[2];
    const float* b_in = (const float*)d_in[3];
    const float* g_in = (const float*)d_in[4];
    const float* be_in= (const float*)d_in[5];
    const float* W_h  = (const float*)d_in[6];
    const float* b_h  = (const float*)d_in[7];
    const float* g_h  = (const float*)d_in[8];
    const float* be_h = (const float*)d_in[9];
    const float* W_out= (const float*)d_in[10];
    const float* b_out= (const float*)d_in[11];
    float* out = (float*)d_out;

    const int n = in_sizes[0] / 128;   // 100000
    const int E = in_sizes[1] / 2;     // 1600000
    const int* src = ei;
    const int* dst = ei + E;

    const int bpb = (n + BUCKETS - 1) / BUCKETS;  // nodes per bucket (391)
    const int HIST_BLOCKS = 256;

    // workspace: binned[E uint2] | eidx[E i32] | partial[HB*256] | ebase[256] | gcur[256]
    //            | dinv[NP f] | starts[NP i] | T[NP*64 u16] | H[NP*64 f]
    const long NP = ((long)n + 127) & ~127L;
    uint2* binned = (uint2*)d_ws;
    int*   eidx   = (int*)(binned + E);
    int*   partial= eidx + E;
    int*   ebase  = partial + HIST_BLOCKS * BUCKETS;
    int*   gcur   = ebase + BUCKETS;
    float* dinv   = (float*)(gcur + BUCKETS);
    int*   starts = (int*)(dinv + NP);
    unsigned short* T = (unsigned short*)(starts + NP);
    float* H      = (float*)(T + NP * 64);

    // ---- CSR-transpose build via 2-level bucket sort ----
    hist_kernel<<<HIST_BLOCKS, 256, 0, stream>>>(dst, E, bpb, partial);
    scan256_kernel<<<1, 256, 0, stream>>>(partial, HIST_BLOCKS, ebase, gcur);
    bin_kernel<<<(E + CHUNK - 1) / CHUNK, 512, 0, stream>>>(src, dst, E, bpb, gcur, binned);
    build_kernel<<<BUCKETS, 256, 0, stream>>>(binned, ebase, E, bpb, n, starts, dinv, eidx);

    const int ggrid = (n + 3) / 4;

    // ---- layer 1 ----
    gemm_kernel<128><<<(n + 63) / 64, 256, 0, stream>>>(x, W_in, dinv, T, n);
    gather_kernel<0><<<ggrid, 256, 0, stream>>>(T, starts, eidx, dinv, b_in, g_in, be_in, H, n, E);

    // ---- layer 2 ----
    gemm_kernel<64><<<(n + 63) / 64, 256, 0, stream>>>(H, W_h, dinv, T, n);
    gather_kernel<0><<<ggrid, 256, 0, stream>>>(T, starts, eidx, dinv, b_h, g_h, be_h, H, n, E);

    // ---- layer 3 (no ReLU/LN, straight to output) ----
    gemm_kernel<64><<<(n + 63) / 64, 256, 0, stream>>>(H, W_out, dinv, T, n);
    gather_kernel<1><<<ggrid, 256, 0, stream>>>(T, starts, eidx, dinv, b_out, nullptr, nullptr, out, n, E);
}